// Round 15
// baseline (170.110 us; speedup 1.0000x reference)
//
#include <hip/hip_runtime.h>

// ---------------- constants ----------------
// B=2048, K_OTH=16, K_LANE=32, N_OTH=32768, N_LANE=65536
// node id ranges: [0,2048) agent | [2048,4096) av | [4096,36864) others | [36864,102400) lanes
// ws layout (floats): ag_h @0 | ag_c @51200 | av_c @102400 | ot_c @153600 | ln_c @972800
// out layout: predict [2048*30*2] @0, env_lane_info [2048*25] @122880
//
// enc (MFMA): one wave (64-thr block) owns ONE 16-node group for all 20 steps.
// Gates[112 packed rows][16 nodes] = 7 MFMA tiles (16x16x32 bf16).
// K layout: k<25 = h, k=25,26 = x0,x1, k=27 = 1.0 (bias), k>=28 = 0.
// Packed gate row p = 4u + r <-> torch row r*25 + u; lane (n=l&15,q=l>>4) C-frag holds
// gates r=0..3 of unit u=4T+q, node n (C layout col=lane&15, row=(lane>>4)*4+reg).
// h/x in LDS as fp32; bf16 hi/lo built on READ via v_cvt_pk_bf16_f32.
// Gate weights pre-scaled by log2e (i,f,o) / 2*log2e (g) -> raw v_exp_f32 (2^x).
// fp32 precision via 3-term bf16 split: Ahi*Bhi + Ahi*Blo + Alo*Bhi.
// rcp-fused activations (r14). r15: gat+dec fused into one kernel (env_code stays in LDS).

typedef __attribute__((ext_vector_type(8))) short s16x8;
typedef __attribute__((ext_vector_type(4))) float fx4;

__device__ __forceinline__ float frcp(float x) { return __builtin_amdgcn_rcpf(x); }
__device__ __forceinline__ float fsig(float x) { return frcp(1.f + __expf(-x)); }
__device__ __forceinline__ float ftanh(float x) { return 1.f - 2.f * frcp(1.f + __expf(2.f * x)); }

__device__ __forceinline__ float exp2p(float x) { float r; asm("v_exp_f32 %0, %1"  : "=v"(r) : "v"(x)); return r; }   // 2^x
__device__ __forceinline__ float exp2m(float x) { float r; asm("v_exp_f32 %0, -%1" : "=v"(r) : "v"(x)); return r; }   // 2^-x

__device__ __forceinline__ unsigned bfhi(float f) {          // RNE f32->bf16 (as u16)
    unsigned b = __float_as_uint(f);
    return (b + 0x7FFFu + ((b >> 16) & 1u)) >> 16;
}
__device__ __forceinline__ float bfval(unsigned h) { return __uint_as_float(h << 16); }

// read 8 fp32 k-elements from LDS, produce bf16 hi + residual-lo fragments
__device__ __forceinline__ void buildB2(const float* L, int q, int n, s16x8& hi, s16x8& lo) {
    float f[8];
#pragma unroll
    for (int e = 0; e < 8; ++e) f[e] = L[(8 * q + e) * 17 + n];   // pairs fuse to ds_read2_b32
    union { unsigned w[4]; s16x8 v; } H, Lo;
#pragma unroll
    for (int i = 0; i < 4; ++i) {
        unsigned hw;
        asm("v_cvt_pk_bf16_f32 %0, %1, %2" : "=v"(hw) : "v"(f[2 * i]), "v"(f[2 * i + 1]));
        const float r0 = f[2 * i]     - __uint_as_float(hw << 16);
        const float r1 = f[2 * i + 1] - __uint_as_float(hw & 0xFFFF0000u);
        unsigned lw;
        asm("v_cvt_pk_bf16_f32 %0, %1, %2" : "=v"(lw) : "v"(r0), "v"(r1));
        H.w[i] = hw; Lo.w[i] = lw;
    }
    hi = H.v; lo = Lo.v;
}

__global__ __launch_bounds__(64, 1) void enc_kernel(
    const float* __restrict__ agent, const float* __restrict__ av,
    const float* __restrict__ oth,   const float* __restrict__ lane,
    const float* __restrict__ agWih, const float* __restrict__ agWhh, const float* __restrict__ agB,
    const float* __restrict__ avWih, const float* __restrict__ avWhh, const float* __restrict__ avB,
    const float* __restrict__ otWih, const float* __restrict__ otWhh, const float* __restrict__ otB,
    float* __restrict__ ws)
{
    __shared__ float hlds[32 * 17];          // [k-slot 0..31][node 0..15], pad 17 words

    const int l = threadIdx.x & 63;
    const int n = l & 15;     // node within group (and A local row, B/D col)
    const int q = l >> 4;     // k-block (and unit offset)
    float* L = hlds;

    const int g0 = blockIdx.x;               // group id 0..6399 (16 nodes each)
    int task;
    if (g0 < 128) task = 0;
    else if (g0 < 256) task = 1;
    else if (g0 < 2304) task = 2;
    else task = 3;                           // lanes use the *agent* encoder (faithful to source bug)

    const float* Whh; const float* Wih; const float* Bp;
    if (task == 1)      { Wih = avWih; Whh = avWhh; Bp = avB; }
    else if (task == 2) { Wih = otWih; Whh = otWhh; Bp = otB; }
    else                { Wih = agWih; Whh = agWhh; Bp = agB; }

    const int node = g0 * 16 + n;
    const float* xp;
    if (task == 0)      xp = agent + node * 100;
    else if (task == 1) xp = av   + (node - 2048)  * 40;
    else if (task == 2) xp = oth  + (node - 4096)  * 40;
    else                xp = lane + (node - 36864) * 40;

    // preload x for steps 5q..5q+4 (lane (n,q) is the step-owner)
    float xv[10];
#pragma unroll
    for (int s = 0; s < 5; ++s) {
        float2 t2 = *reinterpret_cast<const float2*>(xp + 2 * (5 * q + s));
        xv[2 * s] = t2.x; xv[2 * s + 1] = t2.y;
    }

    // ---- A fragments (weights, loop-invariant): 7 tiles x (hi,lo), log2e folded ----
    const float L2E = 1.4426950408889634f;
    s16x8 Ahi[7], Alo[7];
#pragma unroll
    for (int T = 0; T < 7; ++T) {
        const int p = 16 * T + n;            // packed gate row
        const int r = p & 3;
        const int u = p >> 2;
        int row = r * 25 + u;                // torch row
        if (row > 99) row = 99;              // clamp fake rows (u>=25) in-bounds
        const float sc = (r == 2) ? 2.f * L2E : L2E;   // fold log2e (2x for tanh gate)
        float w[8];
        if (q < 3) {
            const float* src = Whh + row * 25 + 8 * q;
#pragma unroll
            for (int e = 0; e < 8; ++e) w[e] = src[e] * sc;
        } else {
            w[0] = Whh[row * 25 + 24] * sc;
            w[1] = Wih[row * 2] * sc;
            w[2] = Wih[row * 2 + 1] * sc;
            w[3] = Bp[row] * sc;
            w[4] = w[5] = w[6] = w[7] = 0.f;
        }
#pragma unroll
        for (int e = 0; e < 8; ++e) {
            unsigned h = bfhi(w[e]);
            unsigned lo = bfhi(w[e] - bfval(h));
            Ahi[T][e] = (short)h;
            Alo[T][e] = (short)lo;
        }
    }

    // ---- init LDS: h(=0) slots, x(0), bias-one, zero pads ----
#pragma unroll
    for (int T = 0; T < 6; ++T) L[(4 * T + q) * 17 + n] = 0.f;
    if (q == 0) {
        L[24 * 17 + n] = 0.f;
        L[25 * 17 + n] = xv[0];
        L[26 * 17 + n] = xv[1];
    }
    if (q == 3) L[27 * 17 + n] = 1.f;
    L[(28 + q) * 17 + n] = 0.f;
    __builtin_amdgcn_wave_barrier();

    s16x8 Bh, Bl;
    buildB2(L, q, n, Bh, Bl);

    float c[7], hv[7];
#pragma unroll
    for (int T = 0; T < 7; ++T) { c[T] = 0.f; hv[T] = 0.f; }

    const fx4 zero4 = {0.f, 0.f, 0.f, 0.f};
    const float TL2E = 2.f * L2E;

#pragma unroll 1
    for (int tt = 0; tt < 4; ++tt) {
#pragma unroll
        for (int s = 0; s < 5; ++s) {
            fx4 acc[7];
#pragma unroll
            for (int T = 0; T < 7; ++T) {
                fx4 a = __builtin_amdgcn_mfma_f32_16x16x32_bf16(Ahi[T], Bh, zero4, 0, 0, 0);
                a = __builtin_amdgcn_mfma_f32_16x16x32_bf16(Ahi[T], Bl, a, 0, 0, 0);
                acc[T] = __builtin_amdgcn_mfma_f32_16x16x32_bf16(Alo[T], Bh, a, 0, 0, 0);
            }
            // rcp-fused cell update: lane owns unit u=4T+q of node n; acc[T] = {i,f,g,o} (log2e pre-scaled)
#pragma unroll
            for (int T = 0; T < 7; ++T) {
                const float A  = exp2m(acc[T][0]);   // 2^-i'
                const float Bv = exp2m(acc[T][1]);   // 2^-f'
                const float Cv = exp2p(acc[T][2]);   // 2^(2*log2e*g)
                const float D  = exp2m(acc[T][3]);   // 2^-o'
                const float a1 = 1.f + A;
                const float b1 = 1.f + Bv;
                const float c1 = 1.f + Cv;
                const float cm = Cv - 1.f;
                const float P  = a1 * c1;
                const float t0 = cm * b1;
                const float num = fmaf(c[T], P, t0);
                const float den = P * b1;
                c[T] = num * frcp(den);
                const float E  = exp2p(c[T] * TL2E);
                const float e1 = 1.f + E;
                const float em = E - 1.f;
                const float d1 = 1.f + D;
                hv[T] = em * frcp(d1 * e1);
            }
            const bool lastStep = (tt == 3) && (s == 4);
            if (!lastStep) {
                // publish h(t+1) as fp32: k=4T+q for T<6, k=24 by q==0 (never touch x/bias slots 25..27)
#pragma unroll
                for (int T = 0; T < 6; ++T) L[(4 * T + q) * 17 + n] = hv[T];
                if (q == 0) L[24 * 17 + n] = hv[6];
                // publish x(t+1) by its owner lane
                if (s < 4) {
                    if (q == tt) {
                        L[25 * 17 + n] = xv[2 * (s + 1)];
                        L[26 * 17 + n] = xv[2 * (s + 1) + 1];
                    }
                } else {
                    if (q == tt + 1) {
                        L[25 * 17 + n] = xv[0];
                        L[26 * 17 + n] = xv[1];
                    }
                }
                __builtin_amdgcn_wave_barrier();
                buildB2(L, q, n, Bh, Bl);
            }
        }
    }

    // ---- store c (and h for agents) ----
    float* dst_c; float* dst_h = nullptr;
    if (task == 0)      { dst_h = ws + node * 25; dst_c = ws + 51200 + node * 25; }
    else if (task == 1) dst_c = ws + 102400 + (node - 2048) * 25;
    else if (task == 2) dst_c = ws + 153600 + (node - 4096) * 25;
    else                dst_c = ws + 972800 + (node - 36864) * 25;
#pragma unroll
    for (int T = 0; T < 7; ++T) {
        const int u = 4 * T + q;
        if (u < 25) {
            dst_c[u] = c[T];
            if (task == 0) dst_h[u] = hv[T];
        }
    }
}

// ---------------- fused GAT + env_lane_info + decoder: one block per env ----------------
__global__ __launch_bounds__(256) void gat_dec_kernel(
    const float* __restrict__ ws,
    const float* __restrict__ gavW, const float* __restrict__ gavAl, const float* __restrict__ gavAr, const float* __restrict__ gavB,
    const float* __restrict__ gotW, const float* __restrict__ gotAl, const float* __restrict__ gotAr, const float* __restrict__ gotB,
    const float* __restrict__ glnW, const float* __restrict__ glnAl, const float* __restrict__ glnAr, const float* __restrict__ glnB,
    const float* __restrict__ deWih, const float* __restrict__ deWhh, const float* __restrict__ deB,
    const float* __restrict__ linW,  const float* __restrict__ linB,
    float* __restrict__ out, float* __restrict__ lane_out)
{
    __shared__ float X[50 * 25];   // 0: ag_c, 1: av_c, 2..17: ot srcs, 18..49: ln srcs
    __shared__ float F[52 * 25];   // 0: fs_av, 1: fd_av(unused), 2: fd_ot, 3: fd_ln, 4..19: fs_ot, 20..51: fs_ln
    __shared__ float er[10];       // [conv(ot=0,ln=1)][head]
    __shared__ float Eo[16 * 5];
    __shared__ float El[32 * 5];
    __shared__ float envc[25];     // env_code (stays in LDS)
    __shared__ float dbuf[28];     // decoder h exchange

    const int tid = threadIdx.x;
    const int b = blockIdx.x;
    const float* agc = ws + 51200;
    const float* avc = ws + 102400;
    const float* otc = ws + 153600;
    const float* lnc = ws + 972800;

    for (int i = tid; i < 1250; i += 256) {
        int r = i / 25, k = i - r * 25;
        float v;
        if (r == 0)      v = agc[b * 25 + k];
        else if (r == 1) v = avc[b * 25 + k];
        else if (r < 18) v = otc[(b * 16 + (r - 2)) * 25 + k];
        else             v = lnc[(b * 32 + (r - 18)) * 25 + k];
        X[i] = v;
    }
    __syncthreads();

    for (int d = tid; d < 1300; d += 256) {
        int row = d / 25, o = d - row * 25;
        const float* W; const float* xs;
        if (row == 0)      { W = gavW; xs = &X[1 * 25]; }
        else if (row == 1) { W = gavW; xs = &X[0]; }
        else if (row == 2) { W = gotW; xs = &X[0]; }
        else if (row == 3) { W = glnW; xs = &X[0]; }
        else if (row < 20) { W = gotW; xs = &X[(2 + row - 4) * 25]; }
        else               { W = glnW; xs = &X[(18 + row - 20) * 25]; }
        float acc = 0.f;
#pragma unroll
        for (int k = 0; k < 25; ++k) acc += W[o * 25 + k] * xs[k];
        F[row * 25 + o] = acc;
    }
    __syncthreads();

    if (tid < 10) {
        int conv = tid / 5, nn = tid - conv * 5;
        const float* ar = conv ? glnAr : gotAr;
        const float* fd = &F[(2 + conv) * 25];
        float acc = 0.f;
#pragma unroll
        for (int f = 0; f < 5; ++f) acc += fd[nn * 5 + f] * ar[nn * 5 + f];
        er[tid] = acc;
    }
    __syncthreads();

    for (int d = tid; d < 240; d += 256) {
        if (d < 80) {
            int i = d / 5, nn = d - i * 5;
            const float* fsrow = &F[(4 + i) * 25];
            float acc = er[nn];
#pragma unroll
            for (int f = 0; f < 5; ++f) acc += fsrow[nn * 5 + f] * gotAl[nn * 5 + f];
            Eo[d] = (acc > 0.f) ? acc : 0.2f * acc;
        } else {
            int d2 = d - 80;
            int i = d2 / 5, nn = d2 - i * 5;
            const float* fsrow = &F[(20 + i) * 25];
            float acc = er[5 + nn];
#pragma unroll
            for (int f = 0; f < 5; ++f) acc += fsrow[nn * 5 + f] * glnAl[nn * 5 + f];
            El[d2] = (acc > 0.f) ? acc : 0.2f * acc;
        }
    }
    __syncthreads();

    if (tid < 10) {
        int conv = tid / 5, nn = tid - conv * 5;
        if (conv == 0) {
            float m = -1e30f;
            for (int i = 0; i < 16; ++i) m = fmaxf(m, Eo[i * 5 + nn]);
            float s = 0.f;
            for (int i = 0; i < 16; ++i) s += __expf(Eo[i * 5 + nn] - m);
            float inv = frcp(s);
            for (int i = 0; i < 16; ++i) Eo[i * 5 + nn] = __expf(Eo[i * 5 + nn] - m) * inv;
        } else {
            float m = -1e30f;
            for (int i = 0; i < 32; ++i) m = fmaxf(m, El[i * 5 + nn]);
            float s = 0.f;
            for (int i = 0; i < 32; ++i) s += __expf(El[i * 5 + nn] - m);
            float inv = frcp(s);
            for (int i = 0; i < 32; ++i) El[i * 5 + nn] = __expf(El[i * 5 + nn] - m) * inv;
        }
    }
    __syncthreads();

    if (tid < 25) {
        const int o = tid, nn = o / 5;
        float v_av = F[o] + gavB[o];
        float s = 0.f;
        for (int i = 0; i < 16; ++i) s += Eo[i * 5 + nn] * F[(4 + i) * 25 + o];
        float v_ot = s + gotB[o];
        s = 0.f;
        for (int i = 0; i < 32; ++i) s += El[i * 5 + nn] * F[(20 + i) * 25 + o];
        float v_ln = s + glnB[o];
        envc[o] = (v_av + v_ot + v_ln) * (1.f / 3.f);
        float m = 0.f;
        for (int i = 0; i < 32; ++i) m += X[(18 + i) * 25 + o];
        lane_out[b * 25 + o] = m * (1.f / 32.f);
        if (o >= 25 - 3) dbuf[o + 3] = 0.f;   // zero pad slots 25..27 (o=22,23,24 -> 25,26,27)
    }
    __syncthreads();

    if (tid >= 64) return;
    // ---- decoder: wave 0, lanes 0..31 own env b (lanes 32..63 mirror — harmless) ----
    const int lane = tid & 63;
    const int u    = lane & 31;
    const int u2   = (u < 25) ? u : 0;
    const bool act = (u < 25) && (lane < 32);

    float U[4][25], Wi[4], Bb[4];
#pragma unroll
    for (int r = 0; r < 4; ++r) {
        const int row = u2 + 25 * r;
#pragma unroll
        for (int k = 0; k < 25; ++k) U[r][k] = deWhh[row * 25 + k];
        Wi[r] = deWih[row];
        Bb[r] = deB[row];
    }
    const int j = u & 1;
    float lw[25];
#pragma unroll
    for (int k = 0; k < 25; ++k) lw[k] = linW[j * 25 + k];
    const float lb = linB[j];

    const float* agh = ws;
    float h[25];
#pragma unroll
    for (int k = 0; k < 25; ++k) h[k] = agh[b * 25 + k];
    float c_own = agc[b * 25 + u2] + envc[u2];

    for (int t = 0; t < 30; ++t) {
        const float tt = 0.1f * (float)t;
        float g[4];
#pragma unroll
        for (int r = 0; r < 4; ++r) {
            float acc = Bb[r] + Wi[r] * tt;
#pragma unroll
            for (int k = 0; k < 25; ++k) acc += U[r][k] * h[k];
            g[r] = acc;
        }
        const float iv = fsig(g[0]);
        const float fv = fsig(g[1]);
        const float gv = ftanh(g[2]);
        const float ov = fsig(g[3]);
        c_own = fv * c_own + iv * gv;
        const float ho = ov * ftanh(c_own);
        if (act) dbuf[u] = ho;
        __builtin_amdgcn_wave_barrier();   // intra-wave LDS exchange; LDS is in-order per wave
#pragma unroll
        for (int k = 0; k < 25; ++k) h[k] = dbuf[k];
        float ov2 = lb;
#pragma unroll
        for (int k = 0; k < 25; ++k) ov2 += lw[k] * h[k];
        if (lane < 2) out[b * 60 + t * 2 + lane] = ov2;
    }
}

// ---------------- launch ----------------
extern "C" void kernel_launch(void* const* d_in, const int* in_sizes, int n_in,
                              void* d_out, int out_size, void* d_ws, size_t ws_size,
                              hipStream_t stream)
{
    const float* agent = (const float*)d_in[0];
    const float* av    = (const float*)d_in[1];
    const float* oth   = (const float*)d_in[2];
    const float* lane  = (const float*)d_in[3];
    const float* agWih = (const float*)d_in[4];
    const float* agWhh = (const float*)d_in[5];
    const float* agB   = (const float*)d_in[6];
    const float* avWih = (const float*)d_in[7];
    const float* avWhh = (const float*)d_in[8];
    const float* avB   = (const float*)d_in[9];
    const float* otWih = (const float*)d_in[10];
    const float* otWhh = (const float*)d_in[11];
    const float* otB   = (const float*)d_in[12];
    const float* deWih = (const float*)d_in[13];
    const float* deWhh = (const float*)d_in[14];
    const float* deB   = (const float*)d_in[15];
    const float* linW  = (const float*)d_in[16];
    const float* linB  = (const float*)d_in[17];
    const float* gavW  = (const float*)d_in[18];
    const float* gavAl = (const float*)d_in[19];
    const float* gavAr = (const float*)d_in[20];
    const float* gavB  = (const float*)d_in[21];
    const float* gotW  = (const float*)d_in[22];
    const float* gotAl = (const float*)d_in[23];
    const float* gotAr = (const float*)d_in[24];
    const float* gotB  = (const float*)d_in[25];
    const float* glnW  = (const float*)d_in[26];
    const float* glnAl = (const float*)d_in[27];
    const float* glnAr = (const float*)d_in[28];
    const float* glnB  = (const float*)d_in[29];
    // d_in[30]=others_dst, d_in[31]=lane_dst: implicit (i/16, i/32), not needed

    float* out = (float*)d_out;
    float* ws  = (float*)d_ws;

    enc_kernel<<<6400, 64, 0, stream>>>(agent, av, oth, lane,
                                        agWih, agWhh, agB,
                                        avWih, avWhh, avB,
                                        otWih, otWhh, otB, ws);

    gat_dec_kernel<<<2048, 256, 0, stream>>>(ws,
                                             gavW, gavAl, gavAr, gavB,
                                             gotW, gotAl, gotAr, gotB,
                                             glnW, glnAl, glnAr, glnB,
                                             deWih, deWhh, deB, linW, linB,
                                             out, out + 122880);
}

// Round 16
// 129.570 us; speedup vs baseline: 1.3129x; 1.3129x over previous
//
#include <hip/hip_runtime.h>

// ---------------- constants ----------------
// B=2048, K_OTH=16, K_LANE=32, N_OTH=32768, N_LANE=65536
// node id ranges: [0,2048) agent | [2048,4096) av | [4096,36864) others | [36864,102400) lanes
// ws layout (floats): ag_h @0 | ag_c @51200 | av_c @102400 | ot_c @153600 | ln_c @972800 | env_code @2611200
// out layout: predict [2048*30*2] @0, env_lane_info [2048*25] @122880
//
// enc (MFMA): one wave (64-thr block) owns ONE 16-node group for all 20 steps.
// Gates[112 packed rows][16 nodes] = 7 MFMA tiles (16x16x32 bf16).
// K layout: k<25 = h, k=25,26 = x0,x1, k=27 = 1.0 (bias), k>=28 = 0.
// Packed gate row p = 4u + r <-> torch row r*25 + u; lane (n=l&15,q=l>>4) C-frag holds
// gates r=0..3 of unit u=4T+q, node n (C layout col=lane&15, row=(lane>>4)*4+reg).
// h/x in LDS as fp32; bf16 hi/lo built on READ via v_cvt_pk_bf16_f32.
// Gate weights pre-scaled by log2e (i,f,o) / 2*log2e (g) -> raw v_exp_f32 (2^x).
// fp32 precision via 3-term bf16 split: Ahi*Bhi + Ahi*Blo + Alo*Bhi.
// rcp-fused activations (r14). r16: REVERT of r15's gat+dec fusion — the fused
// decoder tail ran at block granularity (1 active wave/block, no backfill): 129.7 -> 170 µs.

typedef __attribute__((ext_vector_type(8))) short s16x8;
typedef __attribute__((ext_vector_type(4))) float fx4;

__device__ __forceinline__ float frcp(float x) { return __builtin_amdgcn_rcpf(x); }
__device__ __forceinline__ float fsig(float x) { return frcp(1.f + __expf(-x)); }
__device__ __forceinline__ float ftanh(float x) { return 1.f - 2.f * frcp(1.f + __expf(2.f * x)); }

__device__ __forceinline__ float exp2p(float x) { float r; asm("v_exp_f32 %0, %1"  : "=v"(r) : "v"(x)); return r; }   // 2^x
__device__ __forceinline__ float exp2m(float x) { float r; asm("v_exp_f32 %0, -%1" : "=v"(r) : "v"(x)); return r; }   // 2^-x

__device__ __forceinline__ unsigned bfhi(float f) {          // RNE f32->bf16 (as u16)
    unsigned b = __float_as_uint(f);
    return (b + 0x7FFFu + ((b >> 16) & 1u)) >> 16;
}
__device__ __forceinline__ float bfval(unsigned h) { return __uint_as_float(h << 16); }

// read 8 fp32 k-elements from LDS, produce bf16 hi + residual-lo fragments
__device__ __forceinline__ void buildB2(const float* L, int q, int n, s16x8& hi, s16x8& lo) {
    float f[8];
#pragma unroll
    for (int e = 0; e < 8; ++e) f[e] = L[(8 * q + e) * 17 + n];   // pairs fuse to ds_read2_b32
    union { unsigned w[4]; s16x8 v; } H, Lo;
#pragma unroll
    for (int i = 0; i < 4; ++i) {
        unsigned hw;
        asm("v_cvt_pk_bf16_f32 %0, %1, %2" : "=v"(hw) : "v"(f[2 * i]), "v"(f[2 * i + 1]));
        const float r0 = f[2 * i]     - __uint_as_float(hw << 16);
        const float r1 = f[2 * i + 1] - __uint_as_float(hw & 0xFFFF0000u);
        unsigned lw;
        asm("v_cvt_pk_bf16_f32 %0, %1, %2" : "=v"(lw) : "v"(r0), "v"(r1));
        H.w[i] = hw; Lo.w[i] = lw;
    }
    hi = H.v; lo = Lo.v;
}

__global__ __launch_bounds__(64, 1) void enc_kernel(
    const float* __restrict__ agent, const float* __restrict__ av,
    const float* __restrict__ oth,   const float* __restrict__ lane,
    const float* __restrict__ agWih, const float* __restrict__ agWhh, const float* __restrict__ agB,
    const float* __restrict__ avWih, const float* __restrict__ avWhh, const float* __restrict__ avB,
    const float* __restrict__ otWih, const float* __restrict__ otWhh, const float* __restrict__ otB,
    float* __restrict__ ws)
{
    __shared__ float hlds[32 * 17];          // [k-slot 0..31][node 0..15], pad 17 words

    const int l = threadIdx.x & 63;
    const int n = l & 15;     // node within group (and A local row, B/D col)
    const int q = l >> 4;     // k-block (and unit offset)
    float* L = hlds;

    const int g0 = blockIdx.x;               // group id 0..6399 (16 nodes each)
    int task;
    if (g0 < 128) task = 0;
    else if (g0 < 256) task = 1;
    else if (g0 < 2304) task = 2;
    else task = 3;                           // lanes use the *agent* encoder (faithful to source bug)

    const float* Whh; const float* Wih; const float* Bp;
    if (task == 1)      { Wih = avWih; Whh = avWhh; Bp = avB; }
    else if (task == 2) { Wih = otWih; Whh = otWhh; Bp = otB; }
    else                { Wih = agWih; Whh = agWhh; Bp = agB; }

    const int node = g0 * 16 + n;
    const float* xp;
    if (task == 0)      xp = agent + node * 100;
    else if (task == 1) xp = av   + (node - 2048)  * 40;
    else if (task == 2) xp = oth  + (node - 4096)  * 40;
    else                xp = lane + (node - 36864) * 40;

    // preload x for steps 5q..5q+4 (lane (n,q) is the step-owner)
    float xv[10];
#pragma unroll
    for (int s = 0; s < 5; ++s) {
        float2 t2 = *reinterpret_cast<const float2*>(xp + 2 * (5 * q + s));
        xv[2 * s] = t2.x; xv[2 * s + 1] = t2.y;
    }

    // ---- A fragments (weights, loop-invariant): 7 tiles x (hi,lo), log2e folded ----
    const float L2E = 1.4426950408889634f;
    s16x8 Ahi[7], Alo[7];
#pragma unroll
    for (int T = 0; T < 7; ++T) {
        const int p = 16 * T + n;            // packed gate row
        const int r = p & 3;
        const int u = p >> 2;
        int row = r * 25 + u;                // torch row
        if (row > 99) row = 99;              // clamp fake rows (u>=25) in-bounds
        const float sc = (r == 2) ? 2.f * L2E : L2E;   // fold log2e (2x for tanh gate)
        float w[8];
        if (q < 3) {
            const float* src = Whh + row * 25 + 8 * q;
#pragma unroll
            for (int e = 0; e < 8; ++e) w[e] = src[e] * sc;
        } else {
            w[0] = Whh[row * 25 + 24] * sc;
            w[1] = Wih[row * 2] * sc;
            w[2] = Wih[row * 2 + 1] * sc;
            w[3] = Bp[row] * sc;
            w[4] = w[5] = w[6] = w[7] = 0.f;
        }
#pragma unroll
        for (int e = 0; e < 8; ++e) {
            unsigned h = bfhi(w[e]);
            unsigned lo = bfhi(w[e] - bfval(h));
            Ahi[T][e] = (short)h;
            Alo[T][e] = (short)lo;
        }
    }

    // ---- init LDS: h(=0) slots, x(0), bias-one, zero pads ----
#pragma unroll
    for (int T = 0; T < 6; ++T) L[(4 * T + q) * 17 + n] = 0.f;
    if (q == 0) {
        L[24 * 17 + n] = 0.f;
        L[25 * 17 + n] = xv[0];
        L[26 * 17 + n] = xv[1];
    }
    if (q == 3) L[27 * 17 + n] = 1.f;
    L[(28 + q) * 17 + n] = 0.f;
    __builtin_amdgcn_wave_barrier();

    s16x8 Bh, Bl;
    buildB2(L, q, n, Bh, Bl);

    float c[7], hv[7];
#pragma unroll
    for (int T = 0; T < 7; ++T) { c[T] = 0.f; hv[T] = 0.f; }

    const fx4 zero4 = {0.f, 0.f, 0.f, 0.f};
    const float TL2E = 2.f * L2E;

#pragma unroll 1
    for (int tt = 0; tt < 4; ++tt) {
#pragma unroll
        for (int s = 0; s < 5; ++s) {
            fx4 acc[7];
#pragma unroll
            for (int T = 0; T < 7; ++T) {
                fx4 a = __builtin_amdgcn_mfma_f32_16x16x32_bf16(Ahi[T], Bh, zero4, 0, 0, 0);
                a = __builtin_amdgcn_mfma_f32_16x16x32_bf16(Ahi[T], Bl, a, 0, 0, 0);
                acc[T] = __builtin_amdgcn_mfma_f32_16x16x32_bf16(Alo[T], Bh, a, 0, 0, 0);
            }
            // rcp-fused cell update: lane owns unit u=4T+q of node n; acc[T] = {i,f,g,o} (log2e pre-scaled)
#pragma unroll
            for (int T = 0; T < 7; ++T) {
                const float A  = exp2m(acc[T][0]);   // 2^-i'
                const float Bv = exp2m(acc[T][1]);   // 2^-f'
                const float Cv = exp2p(acc[T][2]);   // 2^(2*log2e*g)
                const float D  = exp2m(acc[T][3]);   // 2^-o'
                const float a1 = 1.f + A;
                const float b1 = 1.f + Bv;
                const float c1 = 1.f + Cv;
                const float cm = Cv - 1.f;
                const float P  = a1 * c1;
                const float t0 = cm * b1;
                const float num = fmaf(c[T], P, t0);
                const float den = P * b1;
                c[T] = num * frcp(den);
                const float E  = exp2p(c[T] * TL2E);
                const float e1 = 1.f + E;
                const float em = E - 1.f;
                const float d1 = 1.f + D;
                hv[T] = em * frcp(d1 * e1);
            }
            const bool lastStep = (tt == 3) && (s == 4);
            if (!lastStep) {
                // publish h(t+1) as fp32: k=4T+q for T<6, k=24 by q==0 (never touch x/bias slots 25..27)
#pragma unroll
                for (int T = 0; T < 6; ++T) L[(4 * T + q) * 17 + n] = hv[T];
                if (q == 0) L[24 * 17 + n] = hv[6];
                // publish x(t+1) by its owner lane
                if (s < 4) {
                    if (q == tt) {
                        L[25 * 17 + n] = xv[2 * (s + 1)];
                        L[26 * 17 + n] = xv[2 * (s + 1) + 1];
                    }
                } else {
                    if (q == tt + 1) {
                        L[25 * 17 + n] = xv[0];
                        L[26 * 17 + n] = xv[1];
                    }
                }
                __builtin_amdgcn_wave_barrier();
                buildB2(L, q, n, Bh, Bl);
            }
        }
    }

    // ---- store c (and h for agents) ----
    float* dst_c; float* dst_h = nullptr;
    if (task == 0)      { dst_h = ws + node * 25; dst_c = ws + 51200 + node * 25; }
    else if (task == 1) dst_c = ws + 102400 + (node - 2048) * 25;
    else if (task == 2) dst_c = ws + 153600 + (node - 4096) * 25;
    else                dst_c = ws + 972800 + (node - 36864) * 25;
#pragma unroll
    for (int T = 0; T < 7; ++T) {
        const int u = 4 * T + q;
        if (u < 25) {
            dst_c[u] = c[T];
            if (task == 0) dst_h[u] = hv[T];
        }
    }
}

// ---------------- GAT + env_lane_info: one block per env ----------------
__global__ __launch_bounds__(256) void gat_kernel(
    const float* __restrict__ ws,
    const float* __restrict__ gavW, const float* __restrict__ gavAl, const float* __restrict__ gavAr, const float* __restrict__ gavB,
    const float* __restrict__ gotW, const float* __restrict__ gotAl, const float* __restrict__ gotAr, const float* __restrict__ gotB,
    const float* __restrict__ glnW, const float* __restrict__ glnAl, const float* __restrict__ glnAr, const float* __restrict__ glnB,
    float* __restrict__ envcode, float* __restrict__ lane_out)
{
    __shared__ float X[50 * 25];   // 0: ag_c, 1: av_c, 2..17: ot srcs, 18..49: ln srcs
    __shared__ float F[52 * 25];   // 0: fs_av, 1: fd_av(unused), 2: fd_ot, 3: fd_ln, 4..19: fs_ot, 20..51: fs_ln
    __shared__ float er[10];       // [conv(ot=0,ln=1)][head]
    __shared__ float Eo[16 * 5];
    __shared__ float El[32 * 5];

    const int tid = threadIdx.x;
    const int b = blockIdx.x;
    const float* agc = ws + 51200;
    const float* avc = ws + 102400;
    const float* otc = ws + 153600;
    const float* lnc = ws + 972800;

    for (int i = tid; i < 1250; i += 256) {
        int r = i / 25, k = i - r * 25;
        float v;
        if (r == 0)      v = agc[b * 25 + k];
        else if (r == 1) v = avc[b * 25 + k];
        else if (r < 18) v = otc[(b * 16 + (r - 2)) * 25 + k];
        else             v = lnc[(b * 32 + (r - 18)) * 25 + k];
        X[i] = v;
    }
    __syncthreads();

    for (int d = tid; d < 1300; d += 256) {
        int row = d / 25, o = d - row * 25;
        const float* W; const float* xs;
        if (row == 0)      { W = gavW; xs = &X[1 * 25]; }
        else if (row == 1) { W = gavW; xs = &X[0]; }
        else if (row == 2) { W = gotW; xs = &X[0]; }
        else if (row == 3) { W = glnW; xs = &X[0]; }
        else if (row < 20) { W = gotW; xs = &X[(2 + row - 4) * 25]; }
        else               { W = glnW; xs = &X[(18 + row - 20) * 25]; }
        float acc = 0.f;
#pragma unroll
        for (int k = 0; k < 25; ++k) acc += W[o * 25 + k] * xs[k];
        F[row * 25 + o] = acc;
    }
    __syncthreads();

    if (tid < 10) {
        int conv = tid / 5, nn = tid - conv * 5;
        const float* ar = conv ? glnAr : gotAr;
        const float* fd = &F[(2 + conv) * 25];
        float acc = 0.f;
#pragma unroll
        for (int f = 0; f < 5; ++f) acc += fd[nn * 5 + f] * ar[nn * 5 + f];
        er[tid] = acc;
    }
    __syncthreads();

    for (int d = tid; d < 240; d += 256) {
        if (d < 80) {
            int i = d / 5, nn = d - i * 5;
            const float* fsrow = &F[(4 + i) * 25];
            float acc = er[nn];
#pragma unroll
            for (int f = 0; f < 5; ++f) acc += fsrow[nn * 5 + f] * gotAl[nn * 5 + f];
            Eo[d] = (acc > 0.f) ? acc : 0.2f * acc;
        } else {
            int d2 = d - 80;
            int i = d2 / 5, nn = d2 - i * 5;
            const float* fsrow = &F[(20 + i) * 25];
            float acc = er[5 + nn];
#pragma unroll
            for (int f = 0; f < 5; ++f) acc += fsrow[nn * 5 + f] * glnAl[nn * 5 + f];
            El[d2] = (acc > 0.f) ? acc : 0.2f * acc;
        }
    }
    __syncthreads();

    if (tid < 10) {
        int conv = tid / 5, nn = tid - conv * 5;
        if (conv == 0) {
            float m = -1e30f;
            for (int i = 0; i < 16; ++i) m = fmaxf(m, Eo[i * 5 + nn]);
            float s = 0.f;
            for (int i = 0; i < 16; ++i) s += __expf(Eo[i * 5 + nn] - m);
            float inv = frcp(s);
            for (int i = 0; i < 16; ++i) Eo[i * 5 + nn] = __expf(Eo[i * 5 + nn] - m) * inv;
        } else {
            float m = -1e30f;
            for (int i = 0; i < 32; ++i) m = fmaxf(m, El[i * 5 + nn]);
            float s = 0.f;
            for (int i = 0; i < 32; ++i) s += __expf(El[i * 5 + nn] - m);
            float inv = frcp(s);
            for (int i = 0; i < 32; ++i) El[i * 5 + nn] = __expf(El[i * 5 + nn] - m) * inv;
        }
    }
    __syncthreads();

    if (tid < 25) {
        const int o = tid, nn = o / 5;
        float v_av = F[o] + gavB[o];
        float s = 0.f;
        for (int i = 0; i < 16; ++i) s += Eo[i * 5 + nn] * F[(4 + i) * 25 + o];
        float v_ot = s + gotB[o];
        s = 0.f;
        for (int i = 0; i < 32; ++i) s += El[i * 5 + nn] * F[(20 + i) * 25 + o];
        float v_ln = s + glnB[o];
        envcode[b * 25 + o] = (v_av + v_ot + v_ln) * (1.f / 3.f);
        float m = 0.f;
        for (int i = 0; i < 32; ++i) m += X[(18 + i) * 25 + o];
        lane_out[b * 25 + o] = m * (1.f / 32.f);
    }
}

// ---------------- decoder: 25 lanes per env, 2 envs per wave, reg weights ----------------
__global__ __launch_bounds__(256) void dec_kernel(
    const float* __restrict__ ws,
    const float* __restrict__ deWih, const float* __restrict__ deWhh, const float* __restrict__ deB,
    const float* __restrict__ linW,  const float* __restrict__ linB,
    float* __restrict__ out)
{
    __shared__ float hbuf[8][28];
    const int tid  = threadIdx.x;
    const int lane = tid & 63;
    const int half = lane >> 5;
    const int u    = lane & 31;
    const int u2   = (u < 25) ? u : 0;
    const bool act = (u < 25);
    const int wglob = (blockIdx.x * 256 + tid) >> 6;
    const int b = wglob * 2 + half;                 // env id
    const int envloc = ((tid >> 6) << 1) + half;    // 0..7 within block

    float U[4][25], Wi[4], Bb[4];
#pragma unroll
    for (int r = 0; r < 4; ++r) {
        const int row = u2 + 25 * r;
#pragma unroll
        for (int k = 0; k < 25; ++k) U[r][k] = deWhh[row * 25 + k];
        Wi[r] = deWih[row];
        Bb[r] = deB[row];
    }
    const int j = u & 1;
    float lw[25];
#pragma unroll
    for (int k = 0; k < 25; ++k) lw[k] = linW[j * 25 + k];
    const float lb = linB[j];

    const float* agh = ws;
    const float* agc = ws + 51200;
    const float* env = ws + 2611200;

    float h[25];
#pragma unroll
    for (int k = 0; k < 25; ++k) h[k] = agh[b * 25 + k];
    float c_own = agc[b * 25 + u2] + env[b * 25 + u2];

    for (int t = 0; t < 30; ++t) {
        const float tt = 0.1f * (float)t;
        float g[4];
#pragma unroll
        for (int r = 0; r < 4; ++r) {
            float acc = Bb[r] + Wi[r] * tt;
#pragma unroll
            for (int k = 0; k < 25; ++k) acc += U[r][k] * h[k];
            g[r] = acc;
        }
        const float iv = fsig(g[0]);
        const float fv = fsig(g[1]);
        const float gv = ftanh(g[2]);
        const float ov = fsig(g[3]);
        c_own = fv * c_own + iv * gv;
        const float ho = ov * ftanh(c_own);
        if (act) hbuf[envloc][u] = ho;
        __builtin_amdgcn_wave_barrier();   // intra-wave LDS exchange; LDS is in-order per wave
#pragma unroll
        for (int k = 0; k < 25; ++k) h[k] = hbuf[envloc][k];
        float ov2 = lb;
#pragma unroll
        for (int k = 0; k < 25; ++k) ov2 += lw[k] * h[k];
        if (u < 2) out[b * 60 + t * 2 + u] = ov2;
    }
}

// ---------------- launch ----------------
extern "C" void kernel_launch(void* const* d_in, const int* in_sizes, int n_in,
                              void* d_out, int out_size, void* d_ws, size_t ws_size,
                              hipStream_t stream)
{
    const float* agent = (const float*)d_in[0];
    const float* av    = (const float*)d_in[1];
    const float* oth   = (const float*)d_in[2];
    const float* lane  = (const float*)d_in[3];
    const float* agWih = (const float*)d_in[4];
    const float* agWhh = (const float*)d_in[5];
    const float* agB   = (const float*)d_in[6];
    const float* avWih = (const float*)d_in[7];
    const float* avWhh = (const float*)d_in[8];
    const float* avB   = (const float*)d_in[9];
    const float* otWih = (const float*)d_in[10];
    const float* otWhh = (const float*)d_in[11];
    const float* otB   = (const float*)d_in[12];
    const float* deWih = (const float*)d_in[13];
    const float* deWhh = (const float*)d_in[14];
    const float* deB   = (const float*)d_in[15];
    const float* linW  = (const float*)d_in[16];
    const float* linB  = (const float*)d_in[17];
    const float* gavW  = (const float*)d_in[18];
    const float* gavAl = (const float*)d_in[19];
    const float* gavAr = (const float*)d_in[20];
    const float* gavB  = (const float*)d_in[21];
    const float* gotW  = (const float*)d_in[22];
    const float* gotAl = (const float*)d_in[23];
    const float* gotAr = (const float*)d_in[24];
    const float* gotB  = (const float*)d_in[25];
    const float* glnW  = (const float*)d_in[26];
    const float* glnAl = (const float*)d_in[27];
    const float* glnAr = (const float*)d_in[28];
    const float* glnB  = (const float*)d_in[29];
    // d_in[30]=others_dst, d_in[31]=lane_dst: implicit (i/16, i/32), not needed

    float* out = (float*)d_out;
    float* ws  = (float*)d_ws;

    enc_kernel<<<6400, 64, 0, stream>>>(agent, av, oth, lane,
                                        agWih, agWhh, agB,
                                        avWih, avWhh, avB,
                                        otWih, otWhh, otB, ws);

    gat_kernel<<<2048, 256, 0, stream>>>(ws,
                                         gavW, gavAl, gavAr, gavB,
                                         gotW, gotAl, gotAr, gotB,
                                         glnW, glnAl, glnAr, glnB,
                                         ws + 2611200, out + 122880);

    dec_kernel<<<256, 256, 0, stream>>>(ws, deWih, deWhh, deB, linW, linB, out);
}

// Round 18
// 129.029 us; speedup vs baseline: 1.3184x; 1.0042x over previous
//
#include <hip/hip_runtime.h>

// ---------------- constants ----------------
// B=2048, K_OTH=16, K_LANE=32, N_OTH=32768, N_LANE=65536
// node id ranges: [0,2048) agent | [2048,4096) av | [4096,36864) others | [36864,102400) lanes
// ws layout (floats): ag_h @0 | ag_c @51200 | av_c @102400 | ot_c @153600 | ln_c @972800 | env_code @2611200
// out layout: predict [2048*30*2] @0, env_lane_info [2048*25] @122880
//
// enc (MFMA): each WAVE owns one 16-node group for all 20 steps; r17/r18 packs TWO
// independent waves per 128-thr block (residency probe: is the ~8/CU wave cap
// per-block or per-wave?). Inner loop identical to r14/r16.
// Gates[112 packed rows][16 nodes] = 7 MFMA tiles (16x16x32 bf16).
// K layout: k<25 = h, k=25,26 = x0,x1, k=27 = 1.0 (bias), k>=28 = 0.
// Packed gate row p = 4u + r <-> torch row r*25 + u; lane (n=l&15,q=l>>4) C-frag holds
// gates r=0..3 of unit u=4T+q, node n (C layout col=lane&15, row=(lane>>4)*4+reg).
// h/x in LDS as fp32; bf16 hi/lo built on READ via v_cvt_pk_bf16_f32.
// Gate weights pre-scaled by log2e (i,f,o) / 2*log2e (g) -> raw v_exp_f32 (2^x).
// fp32 precision via 3-term bf16 split: Ahi*Bhi + Ahi*Blo + Alo*Bh.
// rcp-fused activations (r14).

typedef __attribute__((ext_vector_type(8))) short s16x8;
typedef __attribute__((ext_vector_type(4))) float fx4;

__device__ __forceinline__ float frcp(float x) { return __builtin_amdgcn_rcpf(x); }
__device__ __forceinline__ float fsig(float x) { return frcp(1.f + __expf(-x)); }
__device__ __forceinline__ float ftanh(float x) { return 1.f - 2.f * frcp(1.f + __expf(2.f * x)); }

__device__ __forceinline__ float exp2p(float x) { float r; asm("v_exp_f32 %0, %1"  : "=v"(r) : "v"(x)); return r; }   // 2^x
__device__ __forceinline__ float exp2m(float x) { float r; asm("v_exp_f32 %0, -%1" : "=v"(r) : "v"(x)); return r; }   // 2^-x

__device__ __forceinline__ unsigned bfhi(float f) {          // RNE f32->bf16 (as u16)
    unsigned b = __float_as_uint(f);
    return (b + 0x7FFFu + ((b >> 16) & 1u)) >> 16;
}
__device__ __forceinline__ float bfval(unsigned h) { return __uint_as_float(h << 16); }

// read 8 fp32 k-elements from LDS, produce bf16 hi + residual-lo fragments
__device__ __forceinline__ void buildB2(const float* L, int q, int n, s16x8& hi, s16x8& lo) {
    float f[8];
#pragma unroll
    for (int e = 0; e < 8; ++e) f[e] = L[(8 * q + e) * 17 + n];   // pairs fuse to ds_read2_b32
    union { unsigned w[4]; s16x8 v; } H, Lo;
#pragma unroll
    for (int i = 0; i < 4; ++i) {
        unsigned hw;
        asm("v_cvt_pk_bf16_f32 %0, %1, %2" : "=v"(hw) : "v"(f[2 * i]), "v"(f[2 * i + 1]));
        const float r0 = f[2 * i]     - __uint_as_float(hw << 16);
        const float r1 = f[2 * i + 1] - __uint_as_float(hw & 0xFFFF0000u);
        unsigned lw;
        asm("v_cvt_pk_bf16_f32 %0, %1, %2" : "=v"(lw) : "v"(r0), "v"(r1));
        H.w[i] = hw; Lo.w[i] = lw;
    }
    hi = H.v; lo = Lo.v;
}

__global__ __launch_bounds__(128, 1) void enc_kernel(
    const float* __restrict__ agent, const float* __restrict__ av,
    const float* __restrict__ oth,   const float* __restrict__ lane,
    const float* __restrict__ agWih, const float* __restrict__ agWhh, const float* __restrict__ agB,
    const float* __restrict__ avWih, const float* __restrict__ avWhh, const float* __restrict__ avB,
    const float* __restrict__ otWih, const float* __restrict__ otWhh, const float* __restrict__ otB,
    float* __restrict__ ws)
{
    __shared__ float hlds[2][32 * 17];       // per wave: [k-slot 0..31][node 0..15], pad 17 words

    const int wv = threadIdx.x >> 6;         // wave within block (independent groups)
    const int l  = threadIdx.x & 63;
    const int n  = l & 15;    // node within group (and A local row, B/D col)
    const int q  = l >> 4;    // k-block (and unit offset)
    float* L = hlds[wv];

    const int g0 = blockIdx.x * 2 + wv;      // group id 0..6399 (16 nodes each)
    int task;
    if (g0 < 128) task = 0;
    else if (g0 < 256) task = 1;
    else if (g0 < 2304) task = 2;
    else task = 3;                           // lanes use the *agent* encoder (faithful to source bug)

    const float* Whh; const float* Wih; const float* Bp;
    if (task == 1)      { Wih = avWih; Whh = avWhh; Bp = avB; }
    else if (task == 2) { Wih = otWih; Whh = otWhh; Bp = otB; }
    else                { Wih = agWih; Whh = agWhh; Bp = agB; }

    const int node = g0 * 16 + n;
    const float* xp;
    if (task == 0)      xp = agent + node * 100;
    else if (task == 1) xp = av   + (node - 2048)  * 40;
    else if (task == 2) xp = oth  + (node - 4096)  * 40;
    else                xp = lane + (node - 36864) * 40;

    // preload x for steps 5q..5q+4 (lane (n,q) is the step-owner)
    float xv[10];
#pragma unroll
    for (int s = 0; s < 5; ++s) {
        float2 t2 = *reinterpret_cast<const float2*>(xp + 2 * (5 * q + s));
        xv[2 * s] = t2.x; xv[2 * s + 1] = t2.y;
    }

    // ---- A fragments (weights, loop-invariant): 7 tiles x (hi,lo), log2e folded ----
    const float L2E = 1.4426950408889634f;
    s16x8 Ahi[7], Alo[7];
#pragma unroll
    for (int T = 0; T < 7; ++T) {
        const int p = 16 * T + n;            // packed gate row
        const int r = p & 3;
        const int u = p >> 2;
        int row = r * 25 + u;                // torch row
        if (row > 99) row = 99;              // clamp fake rows (u>=25) in-bounds
        const float sc = (r == 2) ? 2.f * L2E : L2E;   // fold log2e (2x for tanh gate)
        float w[8];
        if (q < 3) {
            const float* src = Whh + row * 25 + 8 * q;
#pragma unroll
            for (int e = 0; e < 8; ++e) w[e] = src[e] * sc;
        } else {
            w[0] = Whh[row * 25 + 24] * sc;
            w[1] = Wih[row * 2] * sc;
            w[2] = Wih[row * 2 + 1] * sc;
            w[3] = Bp[row] * sc;
            w[4] = w[5] = w[6] = w[7] = 0.f;
        }
#pragma unroll
        for (int e = 0; e < 8; ++e) {
            unsigned h = bfhi(w[e]);
            unsigned lo = bfhi(w[e] - bfval(h));
            Ahi[T][e] = (short)h;
            Alo[T][e] = (short)lo;
        }
    }

    // ---- init LDS: h(=0) slots, x(0), bias-one, zero pads ----
#pragma unroll
    for (int T = 0; T < 6; ++T) L[(4 * T + q) * 17 + n] = 0.f;
    if (q == 0) {
        L[24 * 17 + n] = 0.f;
        L[25 * 17 + n] = xv[0];
        L[26 * 17 + n] = xv[1];
    }
    if (q == 3) L[27 * 17 + n] = 1.f;
    L[(28 + q) * 17 + n] = 0.f;
    __builtin_amdgcn_wave_barrier();

    s16x8 Bh, Bl;
    buildB2(L, q, n, Bh, Bl);

    float c[7], hv[7];
#pragma unroll
    for (int T = 0; T < 7; ++T) { c[T] = 0.f; hv[T] = 0.f; }

    const fx4 zero4 = {0.f, 0.f, 0.f, 0.f};
    const float TL2E = 2.f * L2E;

#pragma unroll 1
    for (int tt = 0; tt < 4; ++tt) {
#pragma unroll
        for (int s = 0; s < 5; ++s) {
            fx4 acc[7];
#pragma unroll
            for (int T = 0; T < 7; ++T) {
                fx4 a = __builtin_amdgcn_mfma_f32_16x16x32_bf16(Ahi[T], Bh, zero4, 0, 0, 0);
                a = __builtin_amdgcn_mfma_f32_16x16x32_bf16(Ahi[T], Bl, a, 0, 0, 0);
                acc[T] = __builtin_amdgcn_mfma_f32_16x16x32_bf16(Alo[T], Bh, a, 0, 0, 0);
            }
            // rcp-fused cell update: lane owns unit u=4T+q of node n; acc[T] = {i,f,g,o} (log2e pre-scaled)
#pragma unroll
            for (int T = 0; T < 7; ++T) {
                const float A  = exp2m(acc[T][0]);   // 2^-i'
                const float Bv = exp2m(acc[T][1]);   // 2^-f'
                const float Cv = exp2p(acc[T][2]);   // 2^(2*log2e*g)
                const float D  = exp2m(acc[T][3]);   // 2^-o'
                const float a1 = 1.f + A;
                const float b1 = 1.f + Bv;
                const float c1 = 1.f + Cv;
                const float cm = Cv - 1.f;
                const float P  = a1 * c1;
                const float t0 = cm * b1;
                const float num = fmaf(c[T], P, t0);
                const float den = P * b1;
                c[T] = num * frcp(den);
                const float E  = exp2p(c[T] * TL2E);
                const float e1 = 1.f + E;
                const float em = E - 1.f;
                const float d1 = 1.f + D;
                hv[T] = em * frcp(d1 * e1);
            }
            const bool lastStep = (tt == 3) && (s == 4);
            if (!lastStep) {
                // publish h(t+1) as fp32: k=4T+q for T<6, k=24 by q==0 (never touch x/bias slots 25..27)
#pragma unroll
                for (int T = 0; T < 6; ++T) L[(4 * T + q) * 17 + n] = hv[T];
                if (q == 0) L[24 * 17 + n] = hv[6];
                // publish x(t+1) by its owner lane
                if (s < 4) {
                    if (q == tt) {
                        L[25 * 17 + n] = xv[2 * (s + 1)];
                        L[26 * 17 + n] = xv[2 * (s + 1) + 1];
                    }
                } else {
                    if (q == tt + 1) {
                        L[25 * 17 + n] = xv[0];
                        L[26 * 17 + n] = xv[1];
                    }
                }
                __builtin_amdgcn_wave_barrier();
                buildB2(L, q, n, Bh, Bl);
            }
        }
    }

    // ---- store c (and h for agents) ----
    float* dst_c; float* dst_h = nullptr;
    if (task == 0)      { dst_h = ws + node * 25; dst_c = ws + 51200 + node * 25; }
    else if (task == 1) dst_c = ws + 102400 + (node - 2048) * 25;
    else if (task == 2) dst_c = ws + 153600 + (node - 4096) * 25;
    else                dst_c = ws + 972800 + (node - 36864) * 25;
#pragma unroll
    for (int T = 0; T < 7; ++T) {
        const int u = 4 * T + q;
        if (u < 25) {
            dst_c[u] = c[T];
            if (task == 0) dst_h[u] = hv[T];
        }
    }
}

// ---------------- GAT + env_lane_info: one block per env ----------------
__global__ __launch_bounds__(256) void gat_kernel(
    const float* __restrict__ ws,
    const float* __restrict__ gavW, const float* __restrict__ gavAl, const float* __restrict__ gavAr, const float* __restrict__ gavB,
    const float* __restrict__ gotW, const float* __restrict__ gotAl, const float* __restrict__ gotAr, const float* __restrict__ gotB,
    const float* __restrict__ glnW, const float* __restrict__ glnAl, const float* __restrict__ glnAr, const float* __restrict__ glnB,
    float* __restrict__ envcode, float* __restrict__ lane_out)
{
    __shared__ float X[50 * 25];   // 0: ag_c, 1: av_c, 2..17: ot srcs, 18..49: ln srcs
    __shared__ float F[52 * 25];   // 0: fs_av, 1: fd_av(unused), 2: fd_ot, 3: fd_ln, 4..19: fs_ot, 20..51: fs_ln
    __shared__ float er[10];       // [conv(ot=0,ln=1)][head]
    __shared__ float Eo[16 * 5];
    __shared__ float El[32 * 5];

    const int tid = threadIdx.x;
    const int b = blockIdx.x;
    const float* agc = ws + 51200;
    const float* avc = ws + 102400;
    const float* otc = ws + 153600;
    const float* lnc = ws + 972800;

    for (int i = tid; i < 1250; i += 256) {
        int r = i / 25, k = i - r * 25;
        float v;
        if (r == 0)      v = agc[b * 25 + k];
        else if (r == 1) v = avc[b * 25 + k];
        else if (r < 18) v = otc[(b * 16 + (r - 2)) * 25 + k];
        else             v = lnc[(b * 32 + (r - 18)) * 25 + k];
        X[i] = v;
    }
    __syncthreads();

    for (int d = tid; d < 1300; d += 256) {
        int row = d / 25, o = d - row * 25;
        const float* W; const float* xs;
        if (row == 0)      { W = gavW; xs = &X[1 * 25]; }
        else if (row == 1) { W = gavW; xs = &X[0]; }
        else if (row == 2) { W = gotW; xs = &X[0]; }
        else if (row == 3) { W = glnW; xs = &X[0]; }
        else if (row < 20) { W = gotW; xs = &X[(2 + row - 4) * 25]; }
        else               { W = glnW; xs = &X[(18 + row - 20) * 25]; }
        float acc = 0.f;
#pragma unroll
        for (int k = 0; k < 25; ++k) acc += W[o * 25 + k] * xs[k];
        F[row * 25 + o] = acc;
    }
    __syncthreads();

    if (tid < 10) {
        int conv = tid / 5, nn = tid - conv * 5;
        const float* ar = conv ? glnAr : gotAr;
        const float* fd = &F[(2 + conv) * 25];
        float acc = 0.f;
#pragma unroll
        for (int f = 0; f < 5; ++f) acc += fd[nn * 5 + f] * ar[nn * 5 + f];
        er[tid] = acc;
    }
    __syncthreads();

    for (int d = tid; d < 240; d += 256) {
        if (d < 80) {
            int i = d / 5, nn = d - i * 5;
            const float* fsrow = &F[(4 + i) * 25];
            float acc = er[nn];
#pragma unroll
            for (int f = 0; f < 5; ++f) acc += fsrow[nn * 5 + f] * gotAl[nn * 5 + f];
            Eo[d] = (acc > 0.f) ? acc : 0.2f * acc;
        } else {
            int d2 = d - 80;
            int i = d2 / 5, nn = d2 - i * 5;
            const float* fsrow = &F[(20 + i) * 25];
            float acc = er[5 + nn];
#pragma unroll
            for (int f = 0; f < 5; ++f) acc += fsrow[nn * 5 + f] * glnAl[nn * 5 + f];
            El[d2] = (acc > 0.f) ? acc : 0.2f * acc;
        }
    }
    __syncthreads();

    if (tid < 10) {
        int conv = tid / 5, nn = tid - conv * 5;
        if (conv == 0) {
            float m = -1e30f;
            for (int i = 0; i < 16; ++i) m = fmaxf(m, Eo[i * 5 + nn]);
            float s = 0.f;
            for (int i = 0; i < 16; ++i) s += __expf(Eo[i * 5 + nn] - m);
            float inv = frcp(s);
            for (int i = 0; i < 16; ++i) Eo[i * 5 + nn] = __expf(Eo[i * 5 + nn] - m) * inv;
        } else {
            float m = -1e30f;
            for (int i = 0; i < 32; ++i) m = fmaxf(m, El[i * 5 + nn]);
            float s = 0.f;
            for (int i = 0; i < 32; ++i) s += __expf(El[i * 5 + nn] - m);
            float inv = frcp(s);
            for (int i = 0; i < 32; ++i) El[i * 5 + nn] = __expf(El[i * 5 + nn] - m) * inv;
        }
    }
    __syncthreads();

    if (tid < 25) {
        const int o = tid, nn = o / 5;
        float v_av = F[o] + gavB[o];
        float s = 0.f;
        for (int i = 0; i < 16; ++i) s += Eo[i * 5 + nn] * F[(4 + i) * 25 + o];
        float v_ot = s + gotB[o];
        s = 0.f;
        for (int i = 0; i < 32; ++i) s += El[i * 5 + nn] * F[(20 + i) * 25 + o];
        float v_ln = s + glnB[o];
        envcode[b * 25 + o] = (v_av + v_ot + v_ln) * (1.f / 3.f);
        float m = 0.f;
        for (int i = 0; i < 32; ++i) m += X[(18 + i) * 25 + o];
        lane_out[b * 25 + o] = m * (1.f / 32.f);
    }
}

// ---------------- decoder: 25 lanes per env, 2 envs per wave, reg weights ----------------
__global__ __launch_bounds__(256) void dec_kernel(
    const float* __restrict__ ws,
    const float* __restrict__ deWih, const float* __restrict__ deWhh, const float* __restrict__ deB,
    const float* __restrict__ linW,  const float* __restrict__ linB,
    float* __restrict__ out)
{
    __shared__ float hbuf[8][28];
    const int tid  = threadIdx.x;
    const int lane = tid & 63;
    const int half = lane >> 5;
    const int u    = lane & 31;
    const int u2   = (u < 25) ? u : 0;
    const bool act = (u < 25);
    const int wglob = (blockIdx.x * 256 + tid) >> 6;
    const int b = wglob * 2 + half;                 // env id
    const int envloc = ((tid >> 6) << 1) + half;    // 0..7 within block

    float U[4][25], Wi[4], Bb[4];
#pragma unroll
    for (int r = 0; r < 4; ++r) {
        const int row = u2 + 25 * r;
#pragma unroll
        for (int k = 0; k < 25; ++k) U[r][k] = deWhh[row * 25 + k];
        Wi[r] = deWih[row];
        Bb[r] = deB[row];
    }
    const int j = u & 1;
    float lw[25];
#pragma unroll
    for (int k = 0; k < 25; ++k) lw[k] = linW[j * 25 + k];
    const float lb = linB[j];

    const float* agh = ws;
    const float* agc = ws + 51200;
    const float* env = ws + 2611200;

    float h[25];
#pragma unroll
    for (int k = 0; k < 25; ++k) h[k] = agh[b * 25 + k];
    float c_own = agc[b * 25 + u2] + env[b * 25 + u2];

    for (int t = 0; t < 30; ++t) {
        const float tt = 0.1f * (float)t;
        float g[4];
#pragma unroll
        for (int r = 0; r < 4; ++r) {
            float acc = Bb[r] + Wi[r] * tt;
#pragma unroll
            for (int k = 0; k < 25; ++k) acc += U[r][k] * h[k];
            g[r] = acc;
        }
        const float iv = fsig(g[0]);
        const float fv = fsig(g[1]);
        const float gv = ftanh(g[2]);
        const float ov = fsig(g[3]);
        c_own = fv * c_own + iv * gv;
        const float ho = ov * ftanh(c_own);
        if (act) hbuf[envloc][u] = ho;
        __builtin_amdgcn_wave_barrier();   // intra-wave LDS exchange; LDS is in-order per wave
#pragma unroll
        for (int k = 0; k < 25; ++k) h[k] = hbuf[envloc][k];
        float ov2 = lb;
#pragma unroll
        for (int k = 0; k < 25; ++k) ov2 += lw[k] * h[k];
        if (u < 2) out[b * 60 + t * 2 + u] = ov2;
    }
}

// ---------------- launch ----------------
extern "C" void kernel_launch(void* const* d_in, const int* in_sizes, int n_in,
                              void* d_out, int out_size, void* d_ws, size_t ws_size,
                              hipStream_t stream)
{
    const float* agent = (const float*)d_in[0];
    const float* av    = (const float*)d_in[1];
    const float* oth   = (const float*)d_in[2];
    const float* lane  = (const float*)d_in[3];
    const float* agWih = (const float*)d_in[4];
    const float* agWhh = (const float*)d_in[5];
    const float* agB   = (const float*)d_in[6];
    const float* avWih = (const float*)d_in[7];
    const float* avWhh = (const float*)d_in[8];
    const float* avB   = (const float*)d_in[9];
    const float* otWih = (const float*)d_in[10];
    const float* otWhh = (const float*)d_in[11];
    const float* otB   = (const float*)d_in[12];
    const float* deWih = (const float*)d_in[13];
    const float* deWhh = (const float*)d_in[14];
    const float* deB   = (const float*)d_in[15];
    const float* linW  = (const float*)d_in[16];
    const float* linB  = (const float*)d_in[17];
    const float* gavW  = (const float*)d_in[18];
    const float* gavAl = (const float*)d_in[19];
    const float* gavAr = (const float*)d_in[20];
    const float* gavB  = (const float*)d_in[21];
    const float* gotW  = (const float*)d_in[22];
    const float* gotAl = (const float*)d_in[23];
    const float* gotAr = (const float*)d_in[24];
    const float* gotB  = (const float*)d_in[25];
    const float* glnW  = (const float*)d_in[26];
    const float* glnAl = (const float*)d_in[27];
    const float* glnAr = (const float*)d_in[28];
    const float* glnB  = (const float*)d_in[29];
    // d_in[30]=others_dst, d_in[31]=lane_dst: implicit (i/16, i/32), not needed

    float* out = (float*)d_out;
    float* ws  = (float*)d_ws;

    enc_kernel<<<3200, 128, 0, stream>>>(agent, av, oth, lane,
                                         agWih, agWhh, agB,
                                         avWih, avWhh, avB,
                                         otWih, otWhh, otB, ws);

    gat_kernel<<<2048, 256, 0, stream>>>(ws,
                                         gavW, gavAl, gavAr, gavB,
                                         gotW, gotAl, gotAr, gotB,
                                         glnW, glnAl, glnAr, glnB,
                                         ws + 2611200, out + 122880);

    dec_kernel<<<256, 256, 0, stream>>>(ws, deWih, deWhh, deB, linW, linB, out);
}